// Round 1
// baseline (155.765 us; speedup 1.0000x reference)
//
#include <hip/hip_runtime.h>

#define SEQ 1024
#define TS  64
#define NT  (SEQ/TS)   // 16 tiles

typedef unsigned short u16;
typedef unsigned int   u32;
typedef __bf16 bf16x8 __attribute__((ext_vector_type(8)));
typedef float  f32x4  __attribute__((ext_vector_type(4)));

__device__ __forceinline__ u16 f2bf(float f) {
    u32 u = __float_as_uint(f);
    u += 0x7fffu + ((u >> 16) & 1u);
    return (u16)(u >> 16);
}
__device__ __forceinline__ float bf2f(u16 h) {
    return __uint_as_float(((u32)h) << 16);
}
__device__ __forceinline__ float fast_tanh(float x) {
    float e = __expf(x + x);
    return 1.0f - 2.0f * __builtin_amdgcn_rcpf(e + 1.0f);
}

__global__ __launch_bounds__(256, 3)
void attn_fused(const float* __restrict__ h_t, const float* __restrict__ h_s,
                const float* __restrict__ W_a, const float* __restrict__ U_a,
                const float* __restrict__ V_a, const float* __restrict__ W_c,
                const float* __restrict__ b_c, const float* __restrict__ gamma,
                const float* __restrict__ beta, float* __restrict__ out)
{
    // swizzled bf16 LDS images: element (row,k) -> ushort idx row*128 + (((k>>3)^(row&7))<<3) + (k&7)
    __shared__ u16 Ut[128*128];     // U^T: (col h, k d)
    __shared__ u16 tileB[TS*128];   // h_s tile: (s row, k d)
    __shared__ float htp[128];      // ht_proj, later reused for context
    __shared__ float Vs[128];
    __shared__ float htrow[128];
    __shared__ float redArr[4*16];  // per-wave row weights
    __shared__ float cw[4*128];     // per-wave context partials
    __shared__ float mw[4], lw[4];
    __shared__ float lnp[4], lnq[4];

    const int tid = threadIdx.x;
    const int b   = blockIdx.x;
    const int w   = tid >> 6, l = tid & 63;
    const int lo  = l & 15,  hi = l >> 4;

    if (tid < 128) {
        htrow[tid] = h_t[b*128 + tid];
        Vs[tid]    = V_a[tid];
    }

    // ---- U_a -> bf16, transposed (col-major over h, K contiguous), swizzled ----
    const float4* U4 = (const float4*)U_a;
    #pragma unroll
    for (int i = 0; i < 16; ++i) {
        int f4i = i*256 + tid;
        float4 v = U4[f4i];
        int k  = f4i >> 5;
        int cb = (f4i & 31) * 4;
        float vv[4] = {v.x, v.y, v.z, v.w};
        #pragma unroll
        for (int j = 0; j < 4; ++j) {
            int c = cb + j;
            Ut[c*128 + (((k>>3) ^ (c&7)) << 3) + (k&7)] = f2bf(vv[j]);
        }
    }
    __syncthreads();   // htrow/Vs/Ut ready

    const float4* hs4 = (const float4*)h_s + (size_t)b * (SEQ*128/4);

    // issue tile-0 loads early
    float4 rr[8];
    #pragma unroll
    for (int i = 0; i < 8; ++i) rr[i] = hs4[i*256 + tid];

    // ht_proj = h_t[b] @ W_a  (overlaps with tile-0 loads in flight)
    if (tid < 128) {
        float acc = 0.f;
        #pragma unroll 4
        for (int d = 0; d < 128; ++d) acc += htrow[d] * W_a[d*128 + tid];
        htp[tid] = acc;
    }

    // commit tile 0
    #pragma unroll
    for (int i = 0; i < 8; ++i) {
        int f4i = i*256 + tid;
        int row = f4i >> 5, cf4 = f4i & 31;
        ushort4 pk = { f2bf(rr[i].x), f2bf(rr[i].y), f2bf(rr[i].z), f2bf(rr[i].w) };
        *(ushort4*)&tileB[row*128 + (((cf4>>1) ^ (row&7))<<3) + ((cf4&1)<<2)] = pk;
    }
    __syncthreads();   // tile0 + htp visible

    // per-lane cached htp/V for this lane's 8 MFMA column groups
    float htpR[8], VsR[8];
    #pragma unroll
    for (int n = 0; n < 8; ++n) { htpR[n] = htp[n*16 + lo]; VsR[n] = Vs[n*16 + lo]; }

    // fragment offsets (ushort units)
    const int swz = lo & 7;
    int aOff[4], bOff[4];
    #pragma unroll
    for (int ks = 0; ks < 4; ++ks) {
        int blk = (((ks*4 + hi) ^ swz) << 3);
        aOff[ks] = (w*16 + lo)*128 + blk;
        bOff[ks] = lo*128 + blk;
    }
    const int cblk   = l >> 2;
    const int ctxOff = (l & 3) << 1;

    // online softmax state (m wave-uniform; lsum is hi-group partial; c0/c1 per-lane d=2l,2l+1)
    float m = -1e30f, lsum = 0.f, c0 = 0.f, c1 = 0.f;

    for (int tt = 0; tt < NT; ++tt) {
        if (tt < NT-1) {
            #pragma unroll
            for (int i = 0; i < 8; ++i) rr[i] = hs4[(tt+1)*2048 + i*256 + tid];
        }

        // ---- P = hs_tile @ U  (wave w owns tile rows w*16..w*16+15), fused tanh + V-dot ----
        bf16x8 a0 = *(const bf16x8*)&tileB[aOff[0]];
        bf16x8 a1 = *(const bf16x8*)&tileB[aOff[1]];
        bf16x8 a2 = *(const bf16x8*)&tileB[aOff[2]];
        bf16x8 a3 = *(const bf16x8*)&tileB[aOff[3]];
        float part0 = 0.f, part1 = 0.f, part2 = 0.f, part3 = 0.f;
        #pragma unroll
        for (int n = 0; n < 8; ++n) {
            f32x4 acc = {0.f, 0.f, 0.f, 0.f};
            acc = __builtin_amdgcn_mfma_f32_16x16x32_bf16(a0, *(const bf16x8*)&Ut[n*2048 + bOff[0]], acc, 0, 0, 0);
            acc = __builtin_amdgcn_mfma_f32_16x16x32_bf16(a1, *(const bf16x8*)&Ut[n*2048 + bOff[1]], acc, 0, 0, 0);
            acc = __builtin_amdgcn_mfma_f32_16x16x32_bf16(a2, *(const bf16x8*)&Ut[n*2048 + bOff[2]], acc, 0, 0, 0);
            acc = __builtin_amdgcn_mfma_f32_16x16x32_bf16(a3, *(const bf16x8*)&Ut[n*2048 + bOff[3]], acc, 0, 0, 0);
            float hC = htpR[n], vC = VsR[n];
            part0 += fast_tanh(acc[0] + hC) * vC;
            part1 += fast_tanh(acc[1] + hC) * vC;
            part2 += fast_tanh(acc[2] + hC) * vC;
            part3 += fast_tanh(acc[3] + hC) * vC;
        }
        // reduce across the 16 lanes sharing hi -> full scores for rows hi*4+j
        #pragma unroll
        for (int msk = 1; msk < 16; msk <<= 1) {
            part0 += __shfl_xor(part0, msk);
            part1 += __shfl_xor(part1, msk);
            part2 += __shfl_xor(part2, msk);
            part3 += __shfl_xor(part3, msk);
        }
        // wave-uniform tile max
        float tm = fmaxf(fmaxf(part0, part1), fmaxf(part2, part3));
        tm = fmaxf(tm, __shfl_xor(tm, 16));
        tm = fmaxf(tm, __shfl_xor(tm, 32));
        float nm = fmaxf(m, tm);
        float sc = __expf(m - nm);
        c0 *= sc; c1 *= sc; lsum *= sc; m = nm;
        float w0 = __expf(part0 - m), w1 = __expf(part1 - m);
        float w2 = __expf(part2 - m), w3 = __expf(part3 - m);
        lsum += w0 + w1 + w2 + w3;
        if (lo == 0) {
            redArr[w*16 + hi*4 + 0] = w0;
            redArr[w*16 + hi*4 + 1] = w1;
            redArr[w*16 + hi*4 + 2] = w2;
            redArr[w*16 + hi*4 + 3] = w3;
        }
        // context accumulation over this wave's 16 rows (lane owns d = 2l, 2l+1)
        #pragma unroll
        for (int r = 0; r < 16; ++r) {
            float wr = redArr[w*16 + r];
            u32 ud = *(const u32*)&tileB[(w*16 + r)*128 + ((cblk ^ (r&7)) << 3) + ctxOff];
            c0 += wr * bf2f((u16)(ud & 0xffffu));
            c1 += wr * bf2f((u16)(ud >> 16));
        }
        __syncthreads();   // all waves done reading tileB
        if (tt < NT-1) {
            #pragma unroll
            for (int i = 0; i < 8; ++i) {
                int f4i = i*256 + tid;
                int row = f4i >> 5, cf4 = f4i & 31;
                ushort4 pk = { f2bf(rr[i].x), f2bf(rr[i].y), f2bf(rr[i].z), f2bf(rr[i].w) };
                *(ushort4*)&tileB[row*128 + (((cf4>>1) ^ (row&7))<<3) + ((cf4&1)<<2)] = pk;
            }
        }
        __syncthreads();   // next tile ready
    }

    // ---- merge wave partials ----
    float lt = lsum;
    lt += __shfl_xor(lt, 16);
    lt += __shfl_xor(lt, 32);
    if (l == 0) { mw[w] = m; lw[w] = lt; }
    cw[w*128 + 2*l]     = c0;
    cw[w*128 + 2*l + 1] = c1;
    __syncthreads();

    if (tid < 128) {
        float M = fmaxf(fmaxf(mw[0], mw[1]), fmaxf(mw[2], mw[3]));
        float L = 0.f, C = 0.f;
        #pragma unroll
        for (int wv = 0; wv < 4; ++wv) {
            float s = __expf(mw[wv] - M);
            L += lw[wv] * s;
            C += cw[wv*128 + tid] * s;
        }
        htp[tid] = C / L;   // context (htp LDS no longer needed; cached in regs)
    }
    __syncthreads();

    float av = 0.f;
    if (tid < 128) {
        float acc = b_c[tid];
        #pragma unroll 4
        for (int k = 0; k < 128; ++k) acc += htp[k]   * W_c[k*128 + tid];
        #pragma unroll 4
        for (int k = 0; k < 128; ++k) acc += htrow[k] * W_c[(128 + k)*128 + tid];
        av = fast_tanh(acc);
    }
    // LayerNorm over the 128 attn_vec values (threads 0..127 = waves 0,1)
    float s1 = (tid < 128) ? av : 0.f;
    #pragma unroll
    for (int msk = 1; msk < 64; msk <<= 1) s1 += __shfl_xor(s1, msk);
    if (l == 0) lnp[w] = s1;
    __syncthreads();
    float mu  = (lnp[0] + lnp[1]) * (1.f/128.f);
    float dev = av - mu;
    float s2 = (tid < 128) ? dev*dev : 0.f;
    #pragma unroll
    for (int msk = 1; msk < 64; msk <<= 1) s2 += __shfl_xor(s2, msk);
    if (l == 0) lnq[w] = s2;
    __syncthreads();
    float var = (lnq[0] + lnq[1]) * (1.f/128.f);
    if (tid < 128) {
        out[b*128 + tid] = dev * rsqrtf(var + 1e-3f) * gamma[tid] + beta[tid];
    }
}

extern "C" void kernel_launch(void* const* d_in, const int* in_sizes, int n_in,
                              void* d_out, int out_size, void* d_ws, size_t ws_size,
                              hipStream_t stream) {
    const float* h_t  = (const float*)d_in[0];
    const float* h_s  = (const float*)d_in[1];
    const float* W_a  = (const float*)d_in[2];
    const float* U_a  = (const float*)d_in[3];
    const float* V_a  = (const float*)d_in[4];
    const float* W_c  = (const float*)d_in[5];
    const float* b_c  = (const float*)d_in[6];
    const float* gam  = (const float*)d_in[7];
    const float* bet  = (const float*)d_in[8];
    float* out = (float*)d_out;
    hipLaunchKernelGGL(attn_fused, dim3(1024), dim3(256), 0, stream,
                       h_t, h_s, W_a, U_a, V_a, W_c, b_c, gam, bet, out);
}